// Round 2
// baseline (1840.377 us; speedup 1.0000x reference)
//
#include <hip/hip_runtime.h>

#define N_ELEM 4096
#define BLK 256
#define NPT 16  // elements per thread = N_ELEM / BLK

// |d|^2.4 = (d*d)^1.2 = exp2(1.2 * log2(d*d)); v_log_f32/v_exp_f32 are base-2.
__device__ __forceinline__ float pow24(float d) {
    float d2 = d * d;
    float l = __builtin_amdgcn_logf(d2);       // v_log_f32 (log2)
    return __builtin_amdgcn_exp2f(1.2f * l);   // v_exp_f32 (2^x)
}

__global__ void quant_mse_kernel(const float* __restrict__ x,
                                 float* __restrict__ out,
                                 const int* __restrict__ nump) {
    const int c = blockIdx.x;
    const int tid = threadIdx.x;
    const int lane = tid & 63;
    const int wave = tid >> 6;
    const int num = *nump;

    const float* xrow = x + (size_t)c * N_ELEM;
    float xv[NPT];
#pragma unroll
    for (int e = 0; e < NPT; ++e) xv[e] = xrow[tid + e * BLK];

    // ---- channel min/max (0 included, matching minimum(min,0)/maximum(max,0))
    float mn = 0.0f, mx = 0.0f;
#pragma unroll
    for (int e = 0; e < NPT; ++e) { mn = fminf(mn, xv[e]); mx = fmaxf(mx, xv[e]); }
#pragma unroll
    for (int k = 1; k < 64; k <<= 1) {
        mn = fminf(mn, __shfl_xor(mn, k, 64));
        mx = fmaxf(mx, __shfl_xor(mx, k, 64));
    }
    __shared__ float sred[2][4][16];
    __shared__ float smn[4], smx[4];
    if (lane == 0) { smn[wave] = mn; smx[wave] = mx; }
    __syncthreads();
    mn = fminf(fminf(smn[0], smn[1]), fminf(smn[2], smn[3]));
    mx = fmaxf(fmaxf(smx[0], smx[1]), fmaxf(smx[2], smx[3]));

    const float xrange = mx - mn;
    const float range_div_num = xrange / (float)num;  // matches xrange/num then *i

    float best_score = 1e10f;
    float best_min = mn;  // xmin
    float best_max = mx;  // xmax

    for (int i = 1; i <= num; ++i) {
        const float fi = (float)i;
        const float tmp_max = range_div_num * fi;
        const float s = fmaxf(tmp_max / 15.0f, 1e-8f);  // scale = delta
        const float ns = -s;

        float acc[16];
#pragma unroll
        for (int z = 0; z < 16; ++z) acc[z] = 0.0f;

#pragma unroll
        for (int e = 0; e < NPT; ++e) {
            const float xe = xv[e];
            const float r = rintf(xe / s);  // round-half-even, exact f32 divide
#pragma unroll
            for (int z = 0; z < 16; ++z) {
                // q - zero = clamp(r, -z, 15-z)  (zero == z exactly)
                float v = fminf(fmaxf(r, (float)(-z)), (float)(15 - z));
                float d = fmaf(ns, v, xe);  // x - s*v
                acc[z] += pow24(d);
            }
        }

        // ---- wave butterfly reduce: all lanes end with identical full sums
#pragma unroll
        for (int z = 0; z < 16; ++z) {
#pragma unroll
            for (int k = 1; k < 64; k <<= 1) acc[z] += __shfl_xor(acc[z], k, 64);
        }
        const int buf = i & 1;
        if (lane == 0) {
#pragma unroll
            for (int z = 0; z < 16; ++z) sred[buf][wave][z] = acc[z];
        }
        __syncthreads();

        // ---- every thread redundantly combines waves + tracks best (uniform)
        float bs = 3.4e38f;
        int zb = 0;
#pragma unroll
        for (int z = 0; z < 16; ++z) {
            float sc = ((sred[buf][0][z] + sred[buf][1][z]) + sred[buf][2][z]) + sred[buf][3][z];
            sc *= (1.0f / 4096.0f);  // exact: mean == sum * 2^-12
            if (sc < bs) { bs = sc; zb = z; }  // first minimum kept (argmin semantics)
        }
        if (bs < best_score) {  // strict <, earlier i kept on ties
            best_score = bs;
            float zs = (float)zb * s;
            best_min = -zs;             // new_min = -zbest*delta
            best_max = tmp_max - zs;    // new_max = tmp_max - zbest*delta
        }
    }

    // ---- final params + dequantize
    const float min_neg = fminf(best_min, 0.0f);
    const float max_pos = fmaxf(best_max, 0.0f);
    const float scale = fmaxf((max_pos - min_neg) / 15.0f, 1e-8f);
    const float zero = fminf(fmaxf(0.0f - rintf(min_neg / scale), 0.0f), 15.0f);

    float* orow = out + (size_t)c * N_ELEM;
#pragma unroll
    for (int e = 0; e < NPT; ++e) {
        float q = fminf(fmaxf(rintf(xv[e] / scale) + zero, 0.0f), 15.0f);
        orow[tid + e * BLK] = scale * (q - zero);
    }
}

extern "C" void kernel_launch(void* const* d_in, const int* in_sizes, int n_in,
                              void* d_out, int out_size, void* d_ws, size_t ws_size,
                              hipStream_t stream) {
    const float* x = (const float*)d_in[0];
    const int* nump = (const int*)d_in[1];
    float* out = (float*)d_out;
    const int C = out_size / N_ELEM;
    quant_mse_kernel<<<C, BLK, 0, stream>>>(x, out, nump);
}

// Round 3
// 1485.266 us; speedup vs baseline: 1.2391x; 1.2391x over previous
//
#include <hip/hip_runtime.h>

#define N_ELEM 4096
#define BLK 256

// |d|^2.4 = exp2(1.2 * log2(d*d)); v_log_f32 / v_exp_f32 are base-2.
__device__ __forceinline__ float pow24(float d) {
    float d2 = d * d;
    float l = __builtin_amdgcn_logf(d2);
    return __builtin_amdgcn_exp2f(1.2f * l);
}

__global__ __launch_bounds__(256) void quant_mse_kernel(const float* __restrict__ x,
                                                        float* __restrict__ out,
                                                        const int* __restrict__ nump) {
    const int c = blockIdx.x;
    const int tid = threadIdx.x;
    const int lane = tid & 63;
    const int wave = tid >> 6;
    const int num = *nump;

    __shared__ float sx[N_ELEM];
    __shared__ float fsc[4], ffi[4], fmn[4], fmx[4];

    const float* xrow = x + (size_t)c * N_ELEM;
    for (int idx = tid; idx < N_ELEM; idx += BLK) sx[idx] = xrow[idx];
    __syncthreads();

    // ---- bitonic ascending sort of the channel in LDS (once) ----
    for (int k = 2; k <= N_ELEM; k <<= 1) {
        for (int j = k >> 1; j > 0; j >>= 1) {
            for (int base = tid; base < N_ELEM; base += BLK) {
                int ixj = base ^ j;
                if (ixj > base) {
                    float a = sx[base], b = sx[ixj];
                    bool up = ((base & k) == 0);
                    bool sw = up ? (a > b) : (a < b);
                    if (sw) { sx[base] = b; sx[ixj] = a; }
                }
            }
            __syncthreads();
        }
    }
    // sx is sorted ascending and read-only from here on.

    const float xmn = fminf(sx[0], 0.0f);
    const float xmx = fmaxf(sx[N_ELEM - 1], 0.0f);
    const float xrange = xmx - xmn;
    const float range_div_num = xrange / (float)num;

    // z held by this lane after the value-halving butterfly: bitrev4(lane&15)
    const int zmy = ((lane & 1) << 3) | ((lane & 2) << 1) | ((lane & 4) >> 1) | ((lane & 8) >> 3);
    const float zmyf = (float)zmy;

    float best_score = 1e10f;
    float best_fi = 1e9f;
    float best_min = xmn, best_max = xmx;

    // each wave owns a strided quarter of the i-range; no barriers in this loop
    for (int i = wave + 1; i <= num; i += 4) {
        const float fi = (float)i;
        const float tmp_max = range_div_num * fi;
        const float s = fmaxf(tmp_max / 15.0f, 1e-8f);  // exact div, uniform
        const float ns = -s;
        const float rs = 1.0f / s;                       // exact div, uniform

        float acc[16];
#pragma unroll
        for (int z = 0; z < 16; ++z) acc[z] = 0.0f;

        for (int e = 0; e < 64; ++e) {
            const float xe = sx[(e << 6) + lane];        // sorted slice, ascending in lane
            const float t = xe * rs;
            const float r = rintf(t);
            const float p_in = pow24(fmaf(ns, r, xe));   // interior residual, z-independent
#pragma unroll
            for (int z = 0; z < 16; ++z) acc[z] += p_in;

            // wave-uniform clamp counts from slice extremes (sorted: lane0=min, lane63=max)
            const float rmaxw = __int_as_float(__builtin_amdgcn_readlane(__float_as_int(r), 63));
            const float rminw = __int_as_float(__builtin_amdgcn_readlane(__float_as_int(r), 0));
            const int nhi = (int)fminf(fmaxf(rmaxw, 0.0f), 16.0f);
            const int nlo = (int)fminf(fmaxf(-rminw, 0.0f), 16.0f);

            // upper-clamped: z = 15-j, active iff r > j, d = xe - s*j
#pragma unroll
            for (int j = 0; j < 16; ++j) {
                if (j >= nhi) break;                     // uniform (SGPR) break
                const float jf = (float)j;
                const float ph = pow24(fmaf(ns, jf, xe));
                acc[15 - j] += (r > jf) ? (ph - p_in) : 0.0f;
            }
            // lower-clamped: z = j, active iff r < -j, d = xe + s*j
#pragma unroll
            for (int j = 0; j < 16; ++j) {
                if (j >= nlo) break;
                const float jf = (float)j;
                const float pl = pow24(fmaf(s, jf, xe));
                acc[j] += (r < -jf) ? (pl - p_in) : 0.0f;
            }
        }

        // ---- in-register value-halving butterfly: 16 accs over 64 lanes ----
#pragma unroll
        for (int q = 0; q < 8; ++q) {
            float send = (lane & 1) ? acc[q] : acc[q + 8];
            float keep = (lane & 1) ? acc[q + 8] : acc[q];
            acc[q] = keep + __shfl_xor(send, 1, 64);
        }
#pragma unroll
        for (int q = 0; q < 4; ++q) {
            float send = (lane & 2) ? acc[q] : acc[q + 4];
            float keep = (lane & 2) ? acc[q + 4] : acc[q];
            acc[q] = keep + __shfl_xor(send, 2, 64);
        }
#pragma unroll
        for (int q = 0; q < 2; ++q) {
            float send = (lane & 4) ? acc[q] : acc[q + 2];
            float keep = (lane & 4) ? acc[q + 2] : acc[q];
            acc[q] = keep + __shfl_xor(send, 4, 64);
        }
        {
            float send = (lane & 8) ? acc[0] : acc[1];
            float keep = (lane & 8) ? acc[1] : acc[0];
            acc[0] = keep + __shfl_xor(send, 8, 64);
        }
        acc[0] += __shfl_xor(acc[0], 16, 64);
        acc[0] += __shfl_xor(acc[0], 32, 64);
        float sc = acc[0] * (1.0f / 4096.0f);            // exact: mean = sum * 2^-12

        // lex argmin over z (tie -> smaller z), result uniform across wave
        float bsz = sc, bzz = zmyf;
#pragma unroll
        for (int k = 1; k < 64; k <<= 1) {
            float os = __shfl_xor(bsz, k, 64);
            float oz = __shfl_xor(bzz, k, 64);
            bool take = (os < bsz) || ((os == bsz) && (oz < bzz));
            bsz = take ? os : bsz;
            bzz = take ? oz : bzz;
        }
        if (bsz < best_score) {                          // strict <, ascending i per wave
            best_score = bsz;
            best_fi = fi;
            float zs = bzz * s;
            best_min = -zs;                              // new_min = -zbest*delta
            best_max = tmp_max - zs;                     // new_max = tmp_max - zbest*delta
        }
    }

    // ---- cross-wave lex-min on (score, i): matches sequential strict-< semantics ----
    if (lane == 0) { fsc[wave] = best_score; ffi[wave] = best_fi; fmn[wave] = best_min; fmx[wave] = best_max; }
    __syncthreads();
    float bs = fsc[0], bi = ffi[0], bm = fmn[0], bxv = fmx[0];
#pragma unroll
    for (int w = 1; w < 4; ++w) {
        bool take = (fsc[w] < bs) || ((fsc[w] == bs) && (ffi[w] < bi));
        if (take) { bs = fsc[w]; bi = ffi[w]; bm = fmn[w]; bxv = fmx[w]; }
    }

    const float min_neg = fminf(bm, 0.0f);
    const float max_pos = fmaxf(bxv, 0.0f);
    const float scale = fmaxf((max_pos - min_neg) / 15.0f, 1e-8f);
    const float zero = fminf(fmaxf(0.0f - rintf(min_neg / scale), 0.0f), 15.0f);

    float* orow = out + (size_t)c * N_ELEM;
    for (int idx = tid; idx < N_ELEM; idx += BLK) {
        float xe = xrow[idx];                            // original order, exact div
        float q = fminf(fmaxf(rintf(xe / scale) + zero, 0.0f), 15.0f);
        orow[idx] = scale * (q - zero);
    }
}

extern "C" void kernel_launch(void* const* d_in, const int* in_sizes, int n_in,
                              void* d_out, int out_size, void* d_ws, size_t ws_size,
                              hipStream_t stream) {
    const float* x = (const float*)d_in[0];
    const int* nump = (const int*)d_in[1];
    float* out = (float*)d_out;
    const int C = out_size / N_ELEM;
    quant_mse_kernel<<<C, BLK, 0, stream>>>(x, out, nump);
}